// Round 24
// baseline (306.441 us; speedup 1.0000x reference)
//
#include <hip/hip_runtime.h>
#include <math.h>

#define NROWS 65536
#define DFULL 512
#define HHEADS 8
#define KCODES 512
#define HDIM 64
#define DELTA_S 5e-5f   // S-space cert threshold; cert bound ~1e-5, 5x margin

// ws layout (bytes)
#define WS_LOSS  0          // 64 x f64 slots, 64B stride -> 4096
#define WS_CNT   4096       // u32 padded counter -> 4160
#define WS_HIST  4160       // u32[4096] -> 20544
#define WS_T3    20544      // f32[4096] -> 36928
#define WS_BFRAG 36928      // ushort[8*32*2048] 1MB -> 1085504
#define WS_WL    1085504    // u32[524288] packed (row<<3|h) 2MB -> 3182656
#define WS_CBT   3182656    // f32[8][64][512] transposed codebook 1MB -> 4231232

typedef short bf16x8 __attribute__((ext_vector_type(8)));
typedef float f32x4 __attribute__((ext_vector_type(4)));

__device__ __forceinline__ unsigned short f2bf(float f) {
    unsigned u = __float_as_uint(f);
    unsigned r = (u + 0x7FFFu + ((u >> 16) & 1u)) >> 16;
    return (unsigned short)r;
}
__device__ __forceinline__ float bf2f(unsigned short b) {
    return __uint_as_float(((unsigned)b) << 16);
}

// hi/lo bf16 split of 8 floats via v_cvt_pk_bf16_f32 (HW RNE, == f2bf bitwise)
__device__ __forceinline__ void build_frag(const float* zp, bf16x8& hi, bf16x8& lo) {
    float4 a0 = *(const float4*)zp;
    float4 a1 = *(const float4*)(zp + 4);
    float v[8] = {a0.x, a0.y, a0.z, a0.w, a1.x, a1.y, a1.z, a1.w};
    union { unsigned u[4]; bf16x8 s; } H, L;
    #pragma unroll
    for (int j = 0; j < 4; ++j) {
        asm("v_cvt_pk_bf16_f32 %0, %1, %2"
            : "=v"(H.u[j]) : "v"(v[2 * j]), "v"(v[2 * j + 1]));
        float h0 = __uint_as_float(H.u[j] << 16);
        float h1 = __uint_as_float(H.u[j] & 0xffff0000u);
        float l0 = __fsub_rn(v[2 * j], h0);
        float l1 = __fsub_rn(v[2 * j + 1], h1);
        asm("v_cvt_pk_bf16_f32 %0, %1, %2"
            : "=v"(L.u[j]) : "v"(l0), "v"(l1));
    }
    hi = H.s; lo = L.s;
}

// ---------- fused prep: bfrag (blocks 0-255), cbT (256-1279), t3 (1280-1295) ----------
__global__ void vq_prep_all(const float* __restrict__ cb, float* __restrict__ t3,
                            float* __restrict__ cbT, unsigned short* __restrict__ bfrag) {
    const int b = blockIdx.x;
    const int tid = threadIdx.x;
    if (b < 256) {
        int t = b * 256 + tid;
        int lane = t & 63;
        int pass = (t >> 6) & 1;
        int khalf = (t >> 7) & 1;
        int kt = (t >> 8) & 31;
        int h = t >> 13;
        int n = lane & 15, kg = lane >> 4;
        int kcode = kt * 16 + n;
        int d0 = khalf * 32 + kg * 8;
        const float* src = cb + ((size_t)(h * KCODES + kcode)) * HDIM + d0;
        unsigned short o[8];
        #pragma unroll
        for (int j = 0; j < 8; ++j) {
            float v = src[j];
            unsigned short hi = f2bf(v);
            o[j] = (pass == 0) ? hi : f2bf(__fsub_rn(v, bf2f(hi)));
        }
        *(bf16x8*)(bfrag + (size_t)t * 8) = *(const bf16x8*)o;
    } else if (b < 1280) {
        int t = (b - 256) * 256 + tid;
        int h = t >> 15;
        int d = (t >> 9) & 63;
        int k = t & 511;
        cbT[t] = cb[((size_t)(h * KCODES + k)) * HDIM + d];
    } else {
        int row = (b - 1280) * 256 + tid;
        if (row < HHEADS * KCODES) {
            const float* c = cb + (size_t)row * HDIM;
            float s = __fmul_rn(c[0], c[0]);
            for (int i = 1; i < 64; ++i) s = __fadd_rn(s, __fmul_rn(c[i], c[i]));
            t3[row] = s;
        }
    }
}

// ---------- MFMA prefilter (A-frags staged in LDS) + fused gather ----------
__global__ __launch_bounds__(256, 5) void vq_prefilter(
    const float* __restrict__ z_e, const float* __restrict__ cb,
    const unsigned short* __restrict__ bfrag, const float* __restrict__ t3,
    float* __restrict__ out, float* __restrict__ out_idx,
    unsigned* __restrict__ cnt, unsigned* __restrict__ wl,
    double* __restrict__ loss, unsigned* __restrict__ hist) {
    // A-frag store: 4 waves x 8 frags x 64 lanes x 8 ushorts = 32 KB
    __shared__ __align__(16) unsigned short sA[4][8][64 * 8];
    const int l = threadIdx.x & 63;
    const int wv = threadIdx.x >> 6;
    const int h = blockIdx.x & 7;
    const int wg = (blockIdx.x >> 3) * 4 + wv;   // 0..2047, 32-row group
    const size_t rowbase = (size_t)wg * 32;
    const int m = l & 15, kg = l >> 4;

    // Build frags once and park them in LDS (wave-local region, no barrier).
    {
        bf16x8 hi, lo;
        #pragma unroll
        for (int t = 0; t < 2; ++t) {
            const float* zp = z_e + (rowbase + t * 16 + m) * DFULL + (size_t)h * HDIM + kg * 8;
            build_frag(zp, hi, lo);
            *(bf16x8*)&sA[wv][t * 4 + 0][l * 8] = hi;   // Ah0[t]
            *(bf16x8*)&sA[wv][t * 4 + 1][l * 8] = lo;   // Al0[t]
            build_frag(zp + 32, hi, lo);
            *(bf16x8*)&sA[wv][t * 4 + 2][l * 8] = hi;   // Ah1[t]
            *(bf16x8*)&sA[wv][t * 4 + 3][l * 8] = lo;   // Al1[t]
        }
    }

    const float* t3h = t3 + (size_t)h * KCODES;
    const unsigned short* bf_h = bfrag + (size_t)h * 32 * 2048;

    float m1[8], m2[8];
    int k1[8];
    #pragma unroll
    for (int s = 0; s < 8; ++s) { m1[s] = -INFINITY; m2[s] = -INFINITY; k1[s] = 0; }

    #pragma unroll 2
    for (int kt = 0; kt < 32; ++kt) {
        const unsigned short* bp = bf_h + (size_t)kt * 2048;
        bf16x8 bh0 = *(const bf16x8*)(bp + l * 8);
        bf16x8 bl0 = *(const bf16x8*)(bp + 512 + l * 8);
        bf16x8 bh1 = *(const bf16x8*)(bp + 1024 + l * 8);
        bf16x8 bl1 = *(const bf16x8*)(bp + 1536 + l * 8);
        float nht = __fmul_rn(-0.5f, t3h[kt * 16 + m]);
        int kb = kt * 16 + m;
        #pragma unroll
        for (int t = 0; t < 2; ++t) {
            // A-frags from LDS: cheap ds_read reload each kt (lgkm pipe).
            bf16x8 Ah0 = *(const bf16x8*)&sA[wv][t * 4 + 0][l * 8];
            bf16x8 Al0 = *(const bf16x8*)&sA[wv][t * 4 + 1][l * 8];
            bf16x8 Ah1 = *(const bf16x8*)&sA[wv][t * 4 + 2][l * 8];
            bf16x8 Al1 = *(const bf16x8*)&sA[wv][t * 4 + 3][l * 8];
            f32x4 acc;
            acc[0] = nht; acc[1] = nht; acc[2] = nht; acc[3] = nht;
            acc = __builtin_amdgcn_mfma_f32_16x16x32_bf16(Ah0, bl0, acc, 0, 0, 0);
            acc = __builtin_amdgcn_mfma_f32_16x16x32_bf16(Al0, bh0, acc, 0, 0, 0);
            acc = __builtin_amdgcn_mfma_f32_16x16x32_bf16(Ah0, bh0, acc, 0, 0, 0);
            acc = __builtin_amdgcn_mfma_f32_16x16x32_bf16(Ah1, bl1, acc, 0, 0, 0);
            acc = __builtin_amdgcn_mfma_f32_16x16x32_bf16(Al1, bh1, acc, 0, 0, 0);
            acc = __builtin_amdgcn_mfma_f32_16x16x32_bf16(Ah1, bh1, acc, 0, 0, 0);
            #pragma unroll
            for (int j = 0; j < 4; ++j) {
                const int s = t * 4 + j;
                float S = acc[j];
                float m1o = m1[s];
                m2[s] = fmaxf(m2[s], fminf(S, m1o));   // branchless 2nd-max
                k1[s] = (S > m1o) ? kb : k1[s];
                m1[s] = fmaxf(m1o, S);
            }
        }
    }

    #pragma unroll
    for (int off = 1; off <= 8; off <<= 1) {
        #pragma unroll
        for (int s = 0; s < 8; ++s) {
            float p1 = __shfl_xor(m1[s], off, 64);
            float p2 = __shfl_xor(m2[s], off, 64);
            int pk = __shfl_xor(k1[s], off, 64);
            float nm2 = fmaxf(fminf(m1[s], p1), fmaxf(m2[s], p2));
            bool g = p1 > m1[s];
            k1[s] = g ? pk : k1[s];
            m1[s] = g ? p1 : m1[s];
            m2[s] = nm2;
        }
    }
    // ties (m1==m2) are never certified -> exact recheck resolves first-index.

    unsigned mask = 0;      // bits s (writer-lane local)
    unsigned rowmask = 0;   // bits r = t*16 + kg*4 + j
    if (m == 0) {
        #pragma unroll
        for (int t = 0; t < 2; ++t) {
            #pragma unroll
            for (int j = 0; j < 4; ++j) {
                const int s = t * 4 + j;
                size_t row = rowbase + t * 16 + kg * 4 + j;   // C/D row=(l>>4)*4+j
                out_idx[row * HHEADS + h] = (float)k1[s];
                if (!((m1[s] - m2[s]) > DELTA_S)) {
                    mask |= (1u << s);
                    rowmask |= (1u << (t * 16 + kg * 4 + j));
                }
            }
        }
    }
    int nf = __popc(mask);
    int c0 = __shfl(nf, 0, 64), c1 = __shfl(nf, 16, 64);
    int c2 = __shfl(nf, 32, 64), c3 = __shfl(nf, 48, 64);
    int tot = c0 + c1 + c2 + c3;
    unsigned base = 0;
    if (l == 0 && tot) base = atomicAdd(cnt, (unsigned)tot);
    base = (unsigned)__shfl((int)base, 0, 64);
    if (m == 0 && mask) {
        unsigned off = base + (kg > 0 ? c0 : 0) + (kg > 1 ? c1 : 0) + (kg > 2 ? c2 : 0);
        unsigned mk = mask;
        while (mk) {
            int s = __builtin_ctz(mk);
            mk &= mk - 1;
            unsigned row = (unsigned)rowbase + (unsigned)((s >> 2) * 16 + kg * 4 + (s & 3));
            wl[off++] = (row << 3) | (unsigned)h;
        }
    }
    rowmask |= __shfl_xor(rowmask, 16, 64);
    rowmask |= __shfl_xor(rowmask, 32, 64);
    rowmask = (unsigned)__shfl((int)rowmask, 0, 64);

    // fused gather, float4-vectorized with STATIC slot index; unconditional
    // z_q write (recheck overwrites flagged); loss/hist predicated on flag.
    const float* cbh = cb + (size_t)h * KCODES * HDIM;
    const int sub = l >> 4;        // row-in-quad group
    const int dq = l & 15;         // d-quad
    double lsum = 0.0;
    #pragma unroll
    for (int t = 0; t < 2; ++t) {
        #pragma unroll
        for (int j = 0; j < 4; ++j) {
            const int s = t * 4 + j;                     // static
            int r = t * 16 + sub * 4 + j;                // lane-dependent row
            int ir = __shfl(k1[s], sub * 16, 64);        // writer lane kg*16
            bool fl = (rowmask >> r) & 1u;
            float4 cv = *(const float4*)(cbh + (size_t)ir * HDIM + dq * 4);
            size_t ro = (rowbase + r) * DFULL + (size_t)h * HDIM + dq * 4;
            float4 ze = *(const float4*)(z_e + ro);
            float4 df, oo;
            df.x = __fsub_rn(cv.x, ze.x); oo.x = __fadd_rn(ze.x, df.x);
            df.y = __fsub_rn(cv.y, ze.y); oo.y = __fadd_rn(ze.y, df.y);
            df.z = __fsub_rn(cv.z, ze.z); oo.z = __fadd_rn(ze.z, df.z);
            df.w = __fsub_rn(cv.w, ze.w); oo.w = __fadd_rn(ze.w, df.w);
            *(float4*)(out + ro) = oo;
            if (!fl) {
                lsum += (double)df.x * (double)df.x + (double)df.y * (double)df.y
                      + (double)df.z * (double)df.z + (double)df.w * (double)df.w;
                if (dq == 0) atomicAdd(&hist[h * KCODES + ir], 1u);
            }
        }
    }
    #pragma unroll
    for (int off = 32; off; off >>= 1) lsum += __shfl_xor(lsum, off, 64);
    if (l == 0) atomicAdd(&loss[(wg & 63) * 8], lsum);   // padded slot
}

// ---------- exact recheck + finish for flagged rows ----------
__global__ __launch_bounds__(256, 2) void vq_recheck(
    const float* __restrict__ z_e, const float* __restrict__ cb,
    const float* __restrict__ cbT, const float* __restrict__ t3,
    const unsigned* __restrict__ cnt, const unsigned* __restrict__ wl,
    float* __restrict__ out, float* __restrict__ out_idx,
    double* __restrict__ loss, unsigned* __restrict__ hist) {
    const int lane = threadIdx.x & 63;
    const unsigned wid = blockIdx.x * (blockDim.x >> 6) + (threadIdx.x >> 6);
    const unsigned nw = gridDim.x * (blockDim.x >> 6);
    const unsigned n = cnt[0];
    double lsum = 0.0;                                   // per-wave loss accum
    for (unsigned i = wid; i < n; i += nw) {
        unsigned e = wl[i];
        int h = (int)(e & 7u);
        int row = (int)(e >> 3);
        const float* zp = z_e + (size_t)row * DFULL + (size_t)h * HDIM;   // wave-uniform
        float t1e = __fmul_rn(zp[0], zp[0]);
        #pragma unroll
        for (int d = 1; d < 64; ++d) t1e = __fadd_rn(t1e, __fmul_rn(zp[d], zp[d]));
        const float* ct = cbT + (size_t)h * (HDIM * KCODES);
        float a0 = 0.f, a1 = 0.f, a2 = 0.f, a3 = 0.f;
        float a4 = 0.f, a5 = 0.f, a6 = 0.f, a7 = 0.f;
        #pragma unroll 4
        for (int d = 0; d < 64; ++d) {
            float s = zp[d];                               // uniform
            const float* cd = ct + (size_t)d * KCODES + lane;
            a0 = __fmaf_rn(s, cd[0],   a0);
            a1 = __fmaf_rn(s, cd[64],  a1);
            a2 = __fmaf_rn(s, cd[128], a2);
            a3 = __fmaf_rn(s, cd[192], a3);
            a4 = __fmaf_rn(s, cd[256], a4);
            a5 = __fmaf_rn(s, cd[320], a5);
            a6 = __fmaf_rn(s, cd[384], a6);
            a7 = __fmaf_rn(s, cd[448], a7);
        }
        const float* t3h = t3 + (size_t)h * KCODES;
        float bd = INFINITY;
        int bk = 0x7FFFFFFF;
        float av[8] = {a0, a1, a2, a3, a4, a5, a6, a7};
        #pragma unroll
        for (int c = 0; c < 8; ++c) {
            int k = c * 64 + lane;
            float dk = __fadd_rn(__fsub_rn(t1e, __fmul_rn(2.0f, av[c])), t3h[k]);
            if (dk < bd) { bd = dk; bk = k; }   // ascending k within lane
        }
        #pragma unroll
        for (int off = 1; off <= 32; off <<= 1) {
            float pv = __shfl_xor(bd, off, 64);
            int   pk = __shfl_xor(bk, off, 64);
            if (pv < bd || (pv == bd && pk < bk)) { bd = pv; bk = pk; }
        }
        // finish this row (idx + z_q + loss accum + hist)
        if (lane == 0) out_idx[(size_t)row * HHEADS + h] = (float)bk;
        float cv = cb[((size_t)(h * KCODES + bk)) * HDIM + lane];
        float ze = zp[lane];
        float df = __fsub_rn(cv, ze);
        out[(size_t)row * DFULL + (size_t)h * HDIM + lane] = __fadd_rn(ze, df);
        lsum += (double)df * (double)df;
        if (lane == 0) atomicAdd(&hist[h * KCODES + bk], 1u);
    }
    #pragma unroll
    for (int off = 32; off; off >>= 1) lsum += __shfl_xor(lsum, off, 64);
    if (lane == 0 && lsum != 0.0) atomicAdd(&loss[(wid & 63) * 8], lsum);
}

__global__ void vq_final(const unsigned* __restrict__ hist,
                         const double* __restrict__ loss,
                         float* __restrict__ out) {
    const int tid = threadIdx.x;
    const int wave = tid >> 6;
    const int lane = tid & 63;
    __shared__ double perp[HHEADS];
    double e = 0.0;
    for (int k = lane; k < KCODES; k += 64) {
        double p = (double)hist[wave * KCODES + k] / (double)NROWS;
        e += p * log(p + 1e-10);
    }
    #pragma unroll
    for (int off = 32; off; off >>= 1) e += __shfl_xor(e, off, 64);
    if (lane == 0) perp[wave] = exp(-e);
    __syncthreads();
    if (tid == 0) {
        double mm = 0.0;
        #pragma unroll
        for (int i = 0; i < HHEADS; ++i) mm += perp[i];
        mm /= (double)HHEADS;
        double S = 0.0;
        for (int i = 0; i < 64; ++i) S += loss[i * 8];   // padded slots
        double cl = S / ((double)NROWS * (double)DFULL);
        size_t base = (size_t)NROWS * DFULL + (size_t)NROWS * HHEADS;
        out[base + 0] = (float)cl;
        out[base + 1] = (float)(0.1 * cl);
        out[base + 2] = (float)mm;
    }
}

extern "C" void kernel_launch(void* const* d_in, const int* in_sizes, int n_in,
                              void* d_out, int out_size, void* d_ws, size_t ws_size,
                              hipStream_t stream) {
    const float* z_e = (const float*)d_in[0];
    const float* cb  = (const float*)d_in[1];
    float* out = (float*)d_out;
    float* out_idx = out + (size_t)NROWS * DFULL;
    char* ws = (char*)d_ws;
    double* loss   = (double*)(ws + WS_LOSS);
    unsigned* cnt  = (unsigned*)(ws + WS_CNT);
    unsigned* hist = (unsigned*)(ws + WS_HIST);
    float* t3      = (float*)(ws + WS_T3);
    unsigned short* bfrag = (unsigned short*)(ws + WS_BFRAG);
    unsigned* wl   = (unsigned*)(ws + WS_WL);
    float* cbT     = (float*)(ws + WS_CBT);

    // zero loss slots + counter + histogram
    hipMemsetAsync(ws, 0, WS_HIST + (size_t)HHEADS * KCODES * 4, stream);

    vq_prep_all<<<dim3(1296), dim3(256), 0, stream>>>(cb, t3, cbT, bfrag);
    // 32 rows/wave: 16384 waves = 4096 blocks x 4 waves
    vq_prefilter<<<dim3(4096), dim3(256), 0, stream>>>(z_e, cb, bfrag, t3, out,
                                                       out_idx, cnt, wl, loss, hist);
    vq_recheck<<<dim3(2048), dim3(256), 0, stream>>>(z_e, cb, cbT, t3, cnt, wl,
                                                     out, out_idx, loss, hist);
    vq_final<<<dim3(1), dim3(512), 0, stream>>>(hist, loss, out);
}

// Round 25
// 226.141 us; speedup vs baseline: 1.3551x; 1.3551x over previous
//
#include <hip/hip_runtime.h>
#include <math.h>

#define NROWS 65536
#define DFULL 512
#define HHEADS 8
#define KCODES 512
#define HDIM 64
#define DELTA_S 5e-5f   // S-space cert threshold; cert bound ~1e-5, 5x margin

// ws layout (bytes)
#define WS_LOSS  0          // 64 x f64 slots, 64B stride -> 4096
#define WS_CNT   4096       // u32 padded counter -> 4160
#define WS_HIST  4160       // u32[4096] -> 20544
#define WS_T3    20544      // f32[4096] -> 36928
#define WS_BFRAG 36928      // ushort[8*32*2048] 1MB -> 1085504
#define WS_WL    1085504    // u32[524288] packed (row<<3|h) 2MB -> 3182656
#define WS_CBT   3182656    // f32[8][64][512] transposed codebook 1MB -> 4231232

typedef short bf16x8 __attribute__((ext_vector_type(8)));
typedef float f32x4 __attribute__((ext_vector_type(4)));

__device__ __forceinline__ unsigned short f2bf(float f) {
    unsigned u = __float_as_uint(f);
    unsigned r = (u + 0x7FFFu + ((u >> 16) & 1u)) >> 16;
    return (unsigned short)r;
}
__device__ __forceinline__ float bf2f(unsigned short b) {
    return __uint_as_float(((unsigned)b) << 16);
}

// hi/lo bf16 split of 8 floats via v_cvt_pk_bf16_f32 (HW RNE, == f2bf bitwise)
__device__ __forceinline__ void build_frag(const float* zp, bf16x8& hi, bf16x8& lo) {
    float4 a0 = *(const float4*)zp;
    float4 a1 = *(const float4*)(zp + 4);
    float v[8] = {a0.x, a0.y, a0.z, a0.w, a1.x, a1.y, a1.z, a1.w};
    union { unsigned u[4]; bf16x8 s; } H, L;
    #pragma unroll
    for (int j = 0; j < 4; ++j) {
        asm("v_cvt_pk_bf16_f32 %0, %1, %2"
            : "=v"(H.u[j]) : "v"(v[2 * j]), "v"(v[2 * j + 1]));
        float h0 = __uint_as_float(H.u[j] << 16);
        float h1 = __uint_as_float(H.u[j] & 0xffff0000u);
        float l0 = __fsub_rn(v[2 * j], h0);
        float l1 = __fsub_rn(v[2 * j + 1], h1);
        asm("v_cvt_pk_bf16_f32 %0, %1, %2"
            : "=v"(L.u[j]) : "v"(l0), "v"(l1));
    }
    hi = H.s; lo = L.s;
}

// ---------- fused prep: bfrag (blocks 0-255), cbT (256-1279), t3 (1280-1295) ----------
__global__ void vq_prep_all(const float* __restrict__ cb, float* __restrict__ t3,
                            float* __restrict__ cbT, unsigned short* __restrict__ bfrag) {
    const int b = blockIdx.x;
    const int tid = threadIdx.x;
    if (b < 256) {
        int t = b * 256 + tid;
        int lane = t & 63;
        int pass = (t >> 6) & 1;
        int khalf = (t >> 7) & 1;
        int kt = (t >> 8) & 31;
        int h = t >> 13;
        int n = lane & 15, kg = lane >> 4;
        int kcode = kt * 16 + n;
        int d0 = khalf * 32 + kg * 8;
        const float* src = cb + ((size_t)(h * KCODES + kcode)) * HDIM + d0;
        unsigned short o[8];
        #pragma unroll
        for (int j = 0; j < 8; ++j) {
            float v = src[j];
            unsigned short hi = f2bf(v);
            o[j] = (pass == 0) ? hi : f2bf(__fsub_rn(v, bf2f(hi)));
        }
        *(bf16x8*)(bfrag + (size_t)t * 8) = *(const bf16x8*)o;
    } else if (b < 1280) {
        int t = (b - 256) * 256 + tid;
        int h = t >> 15;
        int d = (t >> 9) & 63;
        int k = t & 511;
        cbT[t] = cb[((size_t)(h * KCODES + k)) * HDIM + d];
    } else {
        int row = (b - 1280) * 256 + tid;
        if (row < HHEADS * KCODES) {
            const float* c = cb + (size_t)row * HDIM;
            float s = __fmul_rn(c[0], c[0]);
            for (int i = 1; i < 64; ++i) s = __fadd_rn(s, __fmul_rn(c[i], c[i]));
            t3[row] = s;
        }
    }
}

// ---------- MFMA prefilter (A-frags staged in LDS) + fused gather ----------
__global__ __launch_bounds__(256, 4) void vq_prefilter(
    const float* __restrict__ z_e, const float* __restrict__ cb,
    const unsigned short* __restrict__ bfrag, const float* __restrict__ t3,
    float* __restrict__ out, float* __restrict__ out_idx,
    unsigned* __restrict__ cnt, unsigned* __restrict__ wl,
    double* __restrict__ loss, unsigned* __restrict__ hist) {
    // A-frag store: 4 waves x 8 frags x 64 lanes x 8 ushorts = 32 KB
    __shared__ __align__(16) unsigned short sA[4][8][64 * 8];
    const int l = threadIdx.x & 63;
    const int wv = threadIdx.x >> 6;
    const int h = blockIdx.x & 7;
    const int wg = (blockIdx.x >> 3) * 4 + wv;   // 0..2047, 32-row group
    const size_t rowbase = (size_t)wg * 32;
    const int m = l & 15, kg = l >> 4;

    // Build frags once and park them in LDS (wave-local region, no barrier).
    {
        bf16x8 hi, lo;
        #pragma unroll
        for (int t = 0; t < 2; ++t) {
            const float* zp = z_e + (rowbase + t * 16 + m) * DFULL + (size_t)h * HDIM + kg * 8;
            build_frag(zp, hi, lo);
            *(bf16x8*)&sA[wv][t * 4 + 0][l * 8] = hi;   // Ah0[t]
            *(bf16x8*)&sA[wv][t * 4 + 1][l * 8] = lo;   // Al0[t]
            build_frag(zp + 32, hi, lo);
            *(bf16x8*)&sA[wv][t * 4 + 2][l * 8] = hi;   // Ah1[t]
            *(bf16x8*)&sA[wv][t * 4 + 3][l * 8] = lo;   // Al1[t]
        }
    }

    const float* t3h = t3 + (size_t)h * KCODES;
    const unsigned short* bf_h = bfrag + (size_t)h * 32 * 2048;

    float m1[8], m2[8];
    int k1[8];
    #pragma unroll
    for (int s = 0; s < 8; ++s) { m1[s] = -INFINITY; m2[s] = -INFINITY; k1[s] = 0; }

    #pragma unroll 2
    for (int kt = 0; kt < 32; ++kt) {
        const unsigned short* bp = bf_h + (size_t)kt * 2048;
        bf16x8 bh0 = *(const bf16x8*)(bp + l * 8);
        bf16x8 bl0 = *(const bf16x8*)(bp + 512 + l * 8);
        bf16x8 bh1 = *(const bf16x8*)(bp + 1024 + l * 8);
        bf16x8 bl1 = *(const bf16x8*)(bp + 1536 + l * 8);
        float nht = __fmul_rn(-0.5f, t3h[kt * 16 + m]);
        int kb = kt * 16 + m;
        #pragma unroll
        for (int t = 0; t < 2; ++t) {
            // A-frags from LDS: cheap ds_read reload each kt (lgkm pipe).
            bf16x8 Ah0 = *(const bf16x8*)&sA[wv][t * 4 + 0][l * 8];
            bf16x8 Al0 = *(const bf16x8*)&sA[wv][t * 4 + 1][l * 8];
            bf16x8 Ah1 = *(const bf16x8*)&sA[wv][t * 4 + 2][l * 8];
            bf16x8 Al1 = *(const bf16x8*)&sA[wv][t * 4 + 3][l * 8];
            f32x4 acc;
            acc[0] = nht; acc[1] = nht; acc[2] = nht; acc[3] = nht;
            acc = __builtin_amdgcn_mfma_f32_16x16x32_bf16(Ah0, bl0, acc, 0, 0, 0);
            acc = __builtin_amdgcn_mfma_f32_16x16x32_bf16(Al0, bh0, acc, 0, 0, 0);
            acc = __builtin_amdgcn_mfma_f32_16x16x32_bf16(Ah0, bh0, acc, 0, 0, 0);
            acc = __builtin_amdgcn_mfma_f32_16x16x32_bf16(Ah1, bl1, acc, 0, 0, 0);
            acc = __builtin_amdgcn_mfma_f32_16x16x32_bf16(Al1, bh1, acc, 0, 0, 0);
            acc = __builtin_amdgcn_mfma_f32_16x16x32_bf16(Ah1, bh1, acc, 0, 0, 0);
            #pragma unroll
            for (int j = 0; j < 4; ++j) {
                const int s = t * 4 + j;
                float S = acc[j];
                float m1o = m1[s];
                m2[s] = fmaxf(m2[s], fminf(S, m1o));   // branchless 2nd-max
                k1[s] = (S > m1o) ? kb : k1[s];
                m1[s] = fmaxf(m1o, S);
            }
        }
    }

    #pragma unroll
    for (int off = 1; off <= 8; off <<= 1) {
        #pragma unroll
        for (int s = 0; s < 8; ++s) {
            float p1 = __shfl_xor(m1[s], off, 64);
            float p2 = __shfl_xor(m2[s], off, 64);
            int pk = __shfl_xor(k1[s], off, 64);
            float nm2 = fmaxf(fminf(m1[s], p1), fmaxf(m2[s], p2));
            bool g = p1 > m1[s];
            k1[s] = g ? pk : k1[s];
            m1[s] = g ? p1 : m1[s];
            m2[s] = nm2;
        }
    }
    // ties (m1==m2) are never certified -> exact recheck resolves first-index.

    unsigned mask = 0;      // bits s (writer-lane local)
    unsigned rowmask = 0;   // bits r = t*16 + kg*4 + j
    if (m == 0) {
        #pragma unroll
        for (int t = 0; t < 2; ++t) {
            #pragma unroll
            for (int j = 0; j < 4; ++j) {
                const int s = t * 4 + j;
                size_t row = rowbase + t * 16 + kg * 4 + j;   // C/D row=(l>>4)*4+j
                out_idx[row * HHEADS + h] = (float)k1[s];
                if (!((m1[s] - m2[s]) > DELTA_S)) {
                    mask |= (1u << s);
                    rowmask |= (1u << (t * 16 + kg * 4 + j));
                }
            }
        }
    }
    int nf = __popc(mask);
    int c0 = __shfl(nf, 0, 64), c1 = __shfl(nf, 16, 64);
    int c2 = __shfl(nf, 32, 64), c3 = __shfl(nf, 48, 64);
    int tot = c0 + c1 + c2 + c3;
    unsigned base = 0;
    if (l == 0 && tot) base = atomicAdd(cnt, (unsigned)tot);
    base = (unsigned)__shfl((int)base, 0, 64);
    if (m == 0 && mask) {
        unsigned off = base + (kg > 0 ? c0 : 0) + (kg > 1 ? c1 : 0) + (kg > 2 ? c2 : 0);
        unsigned mk = mask;
        while (mk) {
            int s = __builtin_ctz(mk);
            mk &= mk - 1;
            unsigned row = (unsigned)rowbase + (unsigned)((s >> 2) * 16 + kg * 4 + (s & 3));
            wl[off++] = (row << 3) | (unsigned)h;
        }
    }
    rowmask |= __shfl_xor(rowmask, 16, 64);
    rowmask |= __shfl_xor(rowmask, 32, 64);
    rowmask = (unsigned)__shfl((int)rowmask, 0, 64);

    // fused gather, float4-vectorized with STATIC slot index; unconditional
    // z_q write (recheck overwrites flagged); loss/hist predicated on flag.
    const float* cbh = cb + (size_t)h * KCODES * HDIM;
    const int sub = l >> 4;        // row-in-quad group
    const int dq = l & 15;         // d-quad
    double lsum = 0.0;
    #pragma unroll
    for (int t = 0; t < 2; ++t) {
        #pragma unroll
        for (int j = 0; j < 4; ++j) {
            const int s = t * 4 + j;                     // static
            int r = t * 16 + sub * 4 + j;                // lane-dependent row
            int ir = __shfl(k1[s], sub * 16, 64);        // writer lane kg*16
            bool fl = (rowmask >> r) & 1u;
            float4 cv = *(const float4*)(cbh + (size_t)ir * HDIM + dq * 4);
            size_t ro = (rowbase + r) * DFULL + (size_t)h * HDIM + dq * 4;
            float4 ze = *(const float4*)(z_e + ro);
            float4 df, oo;
            df.x = __fsub_rn(cv.x, ze.x); oo.x = __fadd_rn(ze.x, df.x);
            df.y = __fsub_rn(cv.y, ze.y); oo.y = __fadd_rn(ze.y, df.y);
            df.z = __fsub_rn(cv.z, ze.z); oo.z = __fadd_rn(ze.z, df.z);
            df.w = __fsub_rn(cv.w, ze.w); oo.w = __fadd_rn(ze.w, df.w);
            *(float4*)(out + ro) = oo;
            if (!fl) {
                lsum += (double)df.x * (double)df.x + (double)df.y * (double)df.y
                      + (double)df.z * (double)df.z + (double)df.w * (double)df.w;
                if (dq == 0) atomicAdd(&hist[h * KCODES + ir], 1u);
            }
        }
    }
    #pragma unroll
    for (int off = 32; off; off >>= 1) lsum += __shfl_xor(lsum, off, 64);
    if (l == 0) atomicAdd(&loss[(wg & 63) * 8], lsum);   // padded slot
}

// ---------- exact recheck + finish for flagged rows ----------
__global__ __launch_bounds__(256, 2) void vq_recheck(
    const float* __restrict__ z_e, const float* __restrict__ cb,
    const float* __restrict__ cbT, const float* __restrict__ t3,
    const unsigned* __restrict__ cnt, const unsigned* __restrict__ wl,
    float* __restrict__ out, float* __restrict__ out_idx,
    double* __restrict__ loss, unsigned* __restrict__ hist) {
    const int lane = threadIdx.x & 63;
    const unsigned wid = blockIdx.x * (blockDim.x >> 6) + (threadIdx.x >> 6);
    const unsigned nw = gridDim.x * (blockDim.x >> 6);
    const unsigned n = cnt[0];
    double lsum = 0.0;                                   // per-wave loss accum
    for (unsigned i = wid; i < n; i += nw) {
        unsigned e = wl[i];
        int h = (int)(e & 7u);
        int row = (int)(e >> 3);
        const float* zp = z_e + (size_t)row * DFULL + (size_t)h * HDIM;   // wave-uniform
        float t1e = __fmul_rn(zp[0], zp[0]);
        #pragma unroll
        for (int d = 1; d < 64; ++d) t1e = __fadd_rn(t1e, __fmul_rn(zp[d], zp[d]));
        const float* ct = cbT + (size_t)h * (HDIM * KCODES);
        float a0 = 0.f, a1 = 0.f, a2 = 0.f, a3 = 0.f;
        float a4 = 0.f, a5 = 0.f, a6 = 0.f, a7 = 0.f;
        #pragma unroll 4
        for (int d = 0; d < 64; ++d) {
            float s = zp[d];                               // uniform
            const float* cd = ct + (size_t)d * KCODES + lane;
            a0 = __fmaf_rn(s, cd[0],   a0);
            a1 = __fmaf_rn(s, cd[64],  a1);
            a2 = __fmaf_rn(s, cd[128], a2);
            a3 = __fmaf_rn(s, cd[192], a3);
            a4 = __fmaf_rn(s, cd[256], a4);
            a5 = __fmaf_rn(s, cd[320], a5);
            a6 = __fmaf_rn(s, cd[384], a6);
            a7 = __fmaf_rn(s, cd[448], a7);
        }
        const float* t3h = t3 + (size_t)h * KCODES;
        float bd = INFINITY;
        int bk = 0x7FFFFFFF;
        float av[8] = {a0, a1, a2, a3, a4, a5, a6, a7};
        #pragma unroll
        for (int c = 0; c < 8; ++c) {
            int k = c * 64 + lane;
            float dk = __fadd_rn(__fsub_rn(t1e, __fmul_rn(2.0f, av[c])), t3h[k]);
            if (dk < bd) { bd = dk; bk = k; }   // ascending k within lane
        }
        #pragma unroll
        for (int off = 1; off <= 32; off <<= 1) {
            float pv = __shfl_xor(bd, off, 64);
            int   pk = __shfl_xor(bk, off, 64);
            if (pv < bd || (pv == bd && pk < bk)) { bd = pv; bk = pk; }
        }
        // finish this row (idx + z_q + loss accum + hist)
        if (lane == 0) out_idx[(size_t)row * HHEADS + h] = (float)bk;
        float cv = cb[((size_t)(h * KCODES + bk)) * HDIM + lane];
        float ze = zp[lane];
        float df = __fsub_rn(cv, ze);
        out[(size_t)row * DFULL + (size_t)h * HDIM + lane] = __fadd_rn(ze, df);
        lsum += (double)df * (double)df;
        if (lane == 0) atomicAdd(&hist[h * KCODES + bk], 1u);
    }
    #pragma unroll
    for (int off = 32; off; off >>= 1) lsum += __shfl_xor(lsum, off, 64);
    if (lane == 0 && lsum != 0.0) atomicAdd(&loss[(wid & 63) * 8], lsum);
}

__global__ void vq_final(const unsigned* __restrict__ hist,
                         const double* __restrict__ loss,
                         float* __restrict__ out) {
    const int tid = threadIdx.x;
    const int wave = tid >> 6;
    const int lane = tid & 63;
    __shared__ double perp[HHEADS];
    double e = 0.0;
    for (int k = lane; k < KCODES; k += 64) {
        double p = (double)hist[wave * KCODES + k] / (double)NROWS;
        e += p * log(p + 1e-10);
    }
    #pragma unroll
    for (int off = 32; off; off >>= 1) e += __shfl_xor(e, off, 64);
    if (lane == 0) perp[wave] = exp(-e);
    __syncthreads();
    if (tid == 0) {
        double mm = 0.0;
        #pragma unroll
        for (int i = 0; i < HHEADS; ++i) mm += perp[i];
        mm /= (double)HHEADS;
        double S = 0.0;
        for (int i = 0; i < 64; ++i) S += loss[i * 8];   // padded slots
        double cl = S / ((double)NROWS * (double)DFULL);
        size_t base = (size_t)NROWS * DFULL + (size_t)NROWS * HHEADS;
        out[base + 0] = (float)cl;
        out[base + 1] = (float)(0.1 * cl);
        out[base + 2] = (float)mm;
    }
}

extern "C" void kernel_launch(void* const* d_in, const int* in_sizes, int n_in,
                              void* d_out, int out_size, void* d_ws, size_t ws_size,
                              hipStream_t stream) {
    const float* z_e = (const float*)d_in[0];
    const float* cb  = (const float*)d_in[1];
    float* out = (float*)d_out;
    float* out_idx = out + (size_t)NROWS * DFULL;
    char* ws = (char*)d_ws;
    double* loss   = (double*)(ws + WS_LOSS);
    unsigned* cnt  = (unsigned*)(ws + WS_CNT);
    unsigned* hist = (unsigned*)(ws + WS_HIST);
    float* t3      = (float*)(ws + WS_T3);
    unsigned short* bfrag = (unsigned short*)(ws + WS_BFRAG);
    unsigned* wl   = (unsigned*)(ws + WS_WL);
    float* cbT     = (float*)(ws + WS_CBT);

    // zero loss slots + counter + histogram
    hipMemsetAsync(ws, 0, WS_HIST + (size_t)HHEADS * KCODES * 4, stream);

    vq_prep_all<<<dim3(1296), dim3(256), 0, stream>>>(cb, t3, cbT, bfrag);
    // 32 rows/wave: 16384 waves = 4096 blocks x 4 waves
    vq_prefilter<<<dim3(4096), dim3(256), 0, stream>>>(z_e, cb, bfrag, t3, out,
                                                       out_idx, cnt, wl, loss, hist);
    vq_recheck<<<dim3(2048), dim3(256), 0, stream>>>(z_e, cb, cbT, t3, cnt, wl,
                                                     out, out_idx, loss, hist);
    vq_final<<<dim3(1), dim3(512), 0, stream>>>(hist, loss, out);
}

// Round 27
// 224.425 us; speedup vs baseline: 1.3654x; 1.0076x over previous
//
#include <hip/hip_runtime.h>
#include <math.h>

#define NROWS 65536
#define DFULL 512
#define HHEADS 8
#define KCODES 512
#define HDIM 64
#define DELTA_S 5e-5f   // S-space cert threshold; cert bound ~1e-5, 5x margin

// ws layout (bytes)
#define WS_LOSS  0          // 64 x f64 slots, 64B stride -> 4096
#define WS_CNT   4096       // u32 padded counter -> 4160
#define WS_HIST  4160       // u32[4096] -> 20544
#define WS_T3    20544      // f32[4096] -> 36928
#define WS_BFRAG 36928      // ushort[8*32*2048] 1MB -> 1085504
#define WS_WL    1085504    // u32[524288] packed (row<<3|h) 2MB -> 3182656
#define WS_CBT   3182656    // f32[8][64][512] transposed codebook 1MB -> 4231232

typedef short bf16x8 __attribute__((ext_vector_type(8)));
typedef float f32x4 __attribute__((ext_vector_type(4)));

__device__ __forceinline__ unsigned short f2bf(float f) {
    unsigned u = __float_as_uint(f);
    unsigned r = (u + 0x7FFFu + ((u >> 16) & 1u)) >> 16;
    return (unsigned short)r;
}
__device__ __forceinline__ float bf2f(unsigned short b) {
    return __uint_as_float(((unsigned)b) << 16);
}

// hi/lo bf16 split of 8 floats via v_cvt_pk_bf16_f32 (HW RNE, == f2bf bitwise)
__device__ __forceinline__ void build_frag(const float* zp, bf16x8& hi, bf16x8& lo) {
    float4 a0 = *(const float4*)zp;
    float4 a1 = *(const float4*)(zp + 4);
    float v[8] = {a0.x, a0.y, a0.z, a0.w, a1.x, a1.y, a1.z, a1.w};
    union { unsigned u[4]; bf16x8 s; } H, L;
    #pragma unroll
    for (int j = 0; j < 4; ++j) {
        asm("v_cvt_pk_bf16_f32 %0, %1, %2"
            : "=v"(H.u[j]) : "v"(v[2 * j]), "v"(v[2 * j + 1]));
        float h0 = __uint_as_float(H.u[j] << 16);
        float h1 = __uint_as_float(H.u[j] & 0xffff0000u);
        float l0 = __fsub_rn(v[2 * j], h0);
        float l1 = __fsub_rn(v[2 * j + 1], h1);
        asm("v_cvt_pk_bf16_f32 %0, %1, %2"
            : "=v"(L.u[j]) : "v"(l0), "v"(l1));
    }
    hi = H.s; lo = L.s;
}

// ---------- fused prep: bfrag (blocks 0-255), cbT (256-1279), t3 (1280-1295) ----------
__global__ void vq_prep_all(const float* __restrict__ cb, float* __restrict__ t3,
                            float* __restrict__ cbT, unsigned short* __restrict__ bfrag) {
    const int b = blockIdx.x;
    const int tid = threadIdx.x;
    if (b < 256) {
        int t = b * 256 + tid;
        int lane = t & 63;
        int pass = (t >> 6) & 1;
        int khalf = (t >> 7) & 1;
        int kt = (t >> 8) & 31;
        int h = t >> 13;
        int n = lane & 15, kg = lane >> 4;
        int kcode = kt * 16 + n;
        int d0 = khalf * 32 + kg * 8;
        const float* src = cb + ((size_t)(h * KCODES + kcode)) * HDIM + d0;
        unsigned short o[8];
        #pragma unroll
        for (int j = 0; j < 8; ++j) {
            float v = src[j];
            unsigned short hi = f2bf(v);
            o[j] = (pass == 0) ? hi : f2bf(__fsub_rn(v, bf2f(hi)));
        }
        *(bf16x8*)(bfrag + (size_t)t * 8) = *(const bf16x8*)o;
    } else if (b < 1280) {
        int t = (b - 256) * 256 + tid;
        int h = t >> 15;
        int d = (t >> 9) & 63;
        int k = t & 511;
        cbT[t] = cb[((size_t)(h * KCODES + k)) * HDIM + d];
    } else {
        int row = (b - 1280) * 256 + tid;
        if (row < HHEADS * KCODES) {
            const float* c = cb + (size_t)row * HDIM;
            float s = __fmul_rn(c[0], c[0]);
            for (int i = 1; i < 64; ++i) s = __fadd_rn(s, __fmul_rn(c[i], c[i]));
            t3[row] = s;
        }
    }
}

// ---------- MFMA prefilter (A-frags staged in LDS) + fused gather ----------
__global__ __launch_bounds__(256, 4) void vq_prefilter(
    const float* __restrict__ z_e, const float* __restrict__ cb,
    const unsigned short* __restrict__ bfrag, const float* __restrict__ t3,
    float* __restrict__ out, float* __restrict__ out_idx,
    unsigned* __restrict__ cnt, unsigned* __restrict__ wl,
    double* __restrict__ loss, unsigned* __restrict__ hist) {
    // A-frag store: 4 waves x 8 frags x 64 lanes x 8 ushorts = 32 KB
    __shared__ __align__(16) unsigned short sA[4][8][64 * 8];
    const int l = threadIdx.x & 63;
    const int wv = threadIdx.x >> 6;
    const int h = blockIdx.x & 7;
    const int wg = (blockIdx.x >> 3) * 4 + wv;   // 0..2047, 32-row group
    const size_t rowbase = (size_t)wg * 32;
    const int m = l & 15, kg = l >> 4;

    // Build frags once and park them in LDS (wave-local region, no barrier).
    {
        bf16x8 hi, lo;
        #pragma unroll
        for (int t = 0; t < 2; ++t) {
            const float* zp = z_e + (rowbase + t * 16 + m) * DFULL + (size_t)h * HDIM + kg * 8;
            build_frag(zp, hi, lo);
            *(bf16x8*)&sA[wv][t * 4 + 0][l * 8] = hi;   // Ah0[t]
            *(bf16x8*)&sA[wv][t * 4 + 1][l * 8] = lo;   // Al0[t]
            build_frag(zp + 32, hi, lo);
            *(bf16x8*)&sA[wv][t * 4 + 2][l * 8] = hi;   // Ah1[t]
            *(bf16x8*)&sA[wv][t * 4 + 3][l * 8] = lo;   // Al1[t]
        }
    }

    const float* t3h = t3 + (size_t)h * KCODES;
    const unsigned short* bf_h = bfrag + (size_t)h * 32 * 2048;

    float m1[8], m2[8];
    int k1[8];
    #pragma unroll
    for (int s = 0; s < 8; ++s) { m1[s] = -INFINITY; m2[s] = -INFINITY; k1[s] = 0; }

    #pragma unroll 2
    for (int kt = 0; kt < 32; ++kt) {
        const unsigned short* bp = bf_h + (size_t)kt * 2048;
        bf16x8 bh0 = *(const bf16x8*)(bp + l * 8);
        bf16x8 bl0 = *(const bf16x8*)(bp + 512 + l * 8);
        bf16x8 bh1 = *(const bf16x8*)(bp + 1024 + l * 8);
        bf16x8 bl1 = *(const bf16x8*)(bp + 1536 + l * 8);
        float nht = __fmul_rn(-0.5f, t3h[kt * 16 + m]);
        int kb = kt * 16 + m;
        #pragma unroll
        for (int t = 0; t < 2; ++t) {
            // A-frags from LDS: cheap ds_read reload each kt (lgkm pipe).
            bf16x8 Ah0 = *(const bf16x8*)&sA[wv][t * 4 + 0][l * 8];
            bf16x8 Al0 = *(const bf16x8*)&sA[wv][t * 4 + 1][l * 8];
            bf16x8 Ah1 = *(const bf16x8*)&sA[wv][t * 4 + 2][l * 8];
            bf16x8 Al1 = *(const bf16x8*)&sA[wv][t * 4 + 3][l * 8];
            f32x4 acc;
            acc[0] = nht; acc[1] = nht; acc[2] = nht; acc[3] = nht;
            acc = __builtin_amdgcn_mfma_f32_16x16x32_bf16(Ah0, bl0, acc, 0, 0, 0);
            acc = __builtin_amdgcn_mfma_f32_16x16x32_bf16(Al0, bh0, acc, 0, 0, 0);
            acc = __builtin_amdgcn_mfma_f32_16x16x32_bf16(Ah0, bh0, acc, 0, 0, 0);
            acc = __builtin_amdgcn_mfma_f32_16x16x32_bf16(Ah1, bl1, acc, 0, 0, 0);
            acc = __builtin_amdgcn_mfma_f32_16x16x32_bf16(Al1, bh1, acc, 0, 0, 0);
            acc = __builtin_amdgcn_mfma_f32_16x16x32_bf16(Ah1, bh1, acc, 0, 0, 0);
            #pragma unroll
            for (int j = 0; j < 4; ++j) {
                const int s = t * 4 + j;
                float S = acc[j];
                float m1o = m1[s];
                m2[s] = fmaxf(m2[s], fminf(S, m1o));   // branchless 2nd-max
                k1[s] = (S > m1o) ? kb : k1[s];
                m1[s] = fmaxf(m1o, S);
            }
        }
    }

    #pragma unroll
    for (int off = 1; off <= 8; off <<= 1) {
        #pragma unroll
        for (int s = 0; s < 8; ++s) {
            float p1 = __shfl_xor(m1[s], off, 64);
            float p2 = __shfl_xor(m2[s], off, 64);
            int pk = __shfl_xor(k1[s], off, 64);
            float nm2 = fmaxf(fminf(m1[s], p1), fmaxf(m2[s], p2));
            bool g = p1 > m1[s];
            k1[s] = g ? pk : k1[s];
            m1[s] = g ? p1 : m1[s];
            m2[s] = nm2;
        }
    }
    // ties (m1==m2) are never certified -> exact recheck resolves first-index.

    unsigned mask = 0;      // bits s (writer-lane local)
    unsigned rowmask = 0;   // bits r = t*16 + kg*4 + j
    if (m == 0) {
        #pragma unroll
        for (int t = 0; t < 2; ++t) {
            #pragma unroll
            for (int j = 0; j < 4; ++j) {
                const int s = t * 4 + j;
                size_t row = rowbase + t * 16 + kg * 4 + j;   // C/D row=(l>>4)*4+j
                out_idx[row * HHEADS + h] = (float)k1[s];
                if (!((m1[s] - m2[s]) > DELTA_S)) {
                    mask |= (1u << s);
                    rowmask |= (1u << (t * 16 + kg * 4 + j));
                }
            }
        }
    }
    int nf = __popc(mask);
    int c0 = __shfl(nf, 0, 64), c1 = __shfl(nf, 16, 64);
    int c2 = __shfl(nf, 32, 64), c3 = __shfl(nf, 48, 64);
    int tot = c0 + c1 + c2 + c3;
    unsigned base = 0;
    if (l == 0 && tot) base = atomicAdd(cnt, (unsigned)tot);
    base = (unsigned)__shfl((int)base, 0, 64);
    if (m == 0 && mask) {
        unsigned off = base + (kg > 0 ? c0 : 0) + (kg > 1 ? c1 : 0) + (kg > 2 ? c2 : 0);
        unsigned mk = mask;
        while (mk) {
            int s = __builtin_ctz(mk);
            mk &= mk - 1;
            unsigned row = (unsigned)rowbase + (unsigned)((s >> 2) * 16 + kg * 4 + (s & 3));
            wl[off++] = (row << 3) | (unsigned)h;
        }
    }
    rowmask |= __shfl_xor(rowmask, 16, 64);
    rowmask |= __shfl_xor(rowmask, 32, 64);
    rowmask = (unsigned)__shfl((int)rowmask, 0, 64);

    // fused gather, float4-vectorized with STATIC slot index; unconditional
    // z_q write (recheck overwrites flagged); loss/hist predicated on flag.
    const float* cbh = cb + (size_t)h * KCODES * HDIM;
    const int sub = l >> 4;        // row-in-quad group
    const int dq = l & 15;         // d-quad
    double lsum = 0.0;
    #pragma unroll
    for (int t = 0; t < 2; ++t) {
        #pragma unroll
        for (int j = 0; j < 4; ++j) {
            const int s = t * 4 + j;                     // static
            int r = t * 16 + sub * 4 + j;                // lane-dependent row
            int ir = __shfl(k1[s], sub * 16, 64);        // writer lane kg*16
            bool fl = (rowmask >> r) & 1u;
            float4 cv = *(const float4*)(cbh + (size_t)ir * HDIM + dq * 4);
            size_t ro = (rowbase + r) * DFULL + (size_t)h * HDIM + dq * 4;
            float4 ze = *(const float4*)(z_e + ro);
            float4 df, oo;
            df.x = __fsub_rn(cv.x, ze.x); oo.x = __fadd_rn(ze.x, df.x);
            df.y = __fsub_rn(cv.y, ze.y); oo.y = __fadd_rn(ze.y, df.y);
            df.z = __fsub_rn(cv.z, ze.z); oo.z = __fadd_rn(ze.z, df.z);
            df.w = __fsub_rn(cv.w, ze.w); oo.w = __fadd_rn(ze.w, df.w);
            *(float4*)(out + ro) = oo;
            if (!fl) {
                lsum += (double)df.x * (double)df.x + (double)df.y * (double)df.y
                      + (double)df.z * (double)df.z + (double)df.w * (double)df.w;
                if (dq == 0) atomicAdd(&hist[h * KCODES + ir], 1u);
            }
        }
    }
    #pragma unroll
    for (int off = 32; off; off >>= 1) lsum += __shfl_xor(lsum, off, 64);
    if (l == 0) atomicAdd(&loss[(wg & 63) * 8], lsum);   // padded slot
}

// ---------- exact recheck + finish for flagged rows ----------
__global__ __launch_bounds__(256, 2) void vq_recheck(
    const float* __restrict__ z_e, const float* __restrict__ cb,
    const float* __restrict__ cbT, const float* __restrict__ t3,
    const unsigned* __restrict__ cnt, const unsigned* __restrict__ wl,
    float* __restrict__ out, float* __restrict__ out_idx,
    double* __restrict__ loss, unsigned* __restrict__ hist) {
    const int lane = threadIdx.x & 63;
    const unsigned wid = blockIdx.x * (blockDim.x >> 6) + (threadIdx.x >> 6);
    const unsigned nw = gridDim.x * (blockDim.x >> 6);
    const unsigned n = cnt[0];
    double lsum = 0.0;                                   // per-wave loss accum
    for (unsigned i = wid; i < n; i += nw) {
        unsigned e = wl[i];
        int h = (int)(e & 7u);
        int row = (int)(e >> 3);
        const float* zp = z_e + (size_t)row * DFULL + (size_t)h * HDIM;   // wave-uniform
        float t1e = __fmul_rn(zp[0], zp[0]);
        #pragma unroll
        for (int d = 1; d < 64; ++d) t1e = __fadd_rn(t1e, __fmul_rn(zp[d], zp[d]));
        const float* ct = cbT + (size_t)h * (HDIM * KCODES);
        float a0 = 0.f, a1 = 0.f, a2 = 0.f, a3 = 0.f;
        float a4 = 0.f, a5 = 0.f, a6 = 0.f, a7 = 0.f;
        #pragma unroll 4
        for (int d = 0; d < 64; ++d) {
            float s = zp[d];                               // uniform
            const float* cd = ct + (size_t)d * KCODES + lane;
            a0 = __fmaf_rn(s, cd[0],   a0);
            a1 = __fmaf_rn(s, cd[64],  a1);
            a2 = __fmaf_rn(s, cd[128], a2);
            a3 = __fmaf_rn(s, cd[192], a3);
            a4 = __fmaf_rn(s, cd[256], a4);
            a5 = __fmaf_rn(s, cd[320], a5);
            a6 = __fmaf_rn(s, cd[384], a6);
            a7 = __fmaf_rn(s, cd[448], a7);
        }
        const float* t3h = t3 + (size_t)h * KCODES;
        float bd = INFINITY;
        int bk = 0x7FFFFFFF;
        float av[8] = {a0, a1, a2, a3, a4, a5, a6, a7};
        #pragma unroll
        for (int c = 0; c < 8; ++c) {
            int k = c * 64 + lane;
            float dk = __fadd_rn(__fsub_rn(t1e, __fmul_rn(2.0f, av[c])), t3h[k]);
            if (dk < bd) { bd = dk; bk = k; }   // ascending k within lane
        }
        #pragma unroll
        for (int off = 1; off <= 32; off <<= 1) {
            float pv = __shfl_xor(bd, off, 64);
            int   pk = __shfl_xor(bk, off, 64);
            if (pv < bd || (pv == bd && pk < bk)) { bd = pv; bk = pk; }
        }
        // finish this row (idx + z_q + loss accum + hist)
        if (lane == 0) out_idx[(size_t)row * HHEADS + h] = (float)bk;
        float cv = cb[((size_t)(h * KCODES + bk)) * HDIM + lane];
        float ze = zp[lane];
        float df = __fsub_rn(cv, ze);
        out[(size_t)row * DFULL + (size_t)h * HDIM + lane] = __fadd_rn(ze, df);
        lsum += (double)df * (double)df;
        if (lane == 0) atomicAdd(&hist[h * KCODES + bk], 1u);
    }
    #pragma unroll
    for (int off = 32; off; off >>= 1) lsum += __shfl_xor(lsum, off, 64);
    if (lane == 0 && lsum != 0.0) atomicAdd(&loss[(wid & 63) * 8], lsum);
}

__global__ void vq_final(const unsigned* __restrict__ hist,
                         const double* __restrict__ loss,
                         float* __restrict__ out) {
    const int tid = threadIdx.x;
    const int wave = tid >> 6;
    const int lane = tid & 63;
    __shared__ double perp[HHEADS];
    double e = 0.0;
    for (int k = lane; k < KCODES; k += 64) {
        double p = (double)hist[wave * KCODES + k] / (double)NROWS;
        e += p * log(p + 1e-10);
    }
    #pragma unroll
    for (int off = 32; off; off >>= 1) e += __shfl_xor(e, off, 64);
    if (lane == 0) perp[wave] = exp(-e);
    __syncthreads();
    if (tid == 0) {
        double mm = 0.0;
        #pragma unroll
        for (int i = 0; i < HHEADS; ++i) mm += perp[i];
        mm /= (double)HHEADS;
        double S = 0.0;
        for (int i = 0; i < 64; ++i) S += loss[i * 8];   // padded slots
        double cl = S / ((double)NROWS * (double)DFULL);
        size_t base = (size_t)NROWS * DFULL + (size_t)NROWS * HHEADS;
        out[base + 0] = (float)cl;
        out[base + 1] = (float)(0.1 * cl);
        out[base + 2] = (float)mm;
    }
}

extern "C" void kernel_launch(void* const* d_in, const int* in_sizes, int n_in,
                              void* d_out, int out_size, void* d_ws, size_t ws_size,
                              hipStream_t stream) {
    const float* z_e = (const float*)d_in[0];
    const float* cb  = (const float*)d_in[1];
    float* out = (float*)d_out;
    float* out_idx = out + (size_t)NROWS * DFULL;
    char* ws = (char*)d_ws;
    double* loss   = (double*)(ws + WS_LOSS);
    unsigned* cnt  = (unsigned*)(ws + WS_CNT);
    unsigned* hist = (unsigned*)(ws + WS_HIST);
    float* t3      = (float*)(ws + WS_T3);
    unsigned short* bfrag = (unsigned short*)(ws + WS_BFRAG);
    unsigned* wl   = (unsigned*)(ws + WS_WL);
    float* cbT     = (float*)(ws + WS_CBT);

    // zero loss slots + counter + histogram
    hipMemsetAsync(ws, 0, WS_HIST + (size_t)HHEADS * KCODES * 4, stream);

    vq_prep_all<<<dim3(1296), dim3(256), 0, stream>>>(cb, t3, cbT, bfrag);
    // 32 rows/wave: 16384 waves = 4096 blocks x 4 waves
    vq_prefilter<<<dim3(4096), dim3(256), 0, stream>>>(z_e, cb, bfrag, t3, out,
                                                       out_idx, cnt, wl, loss, hist);
    vq_recheck<<<dim3(2048), dim3(256), 0, stream>>>(z_e, cb, cbT, t3, cnt, wl,
                                                     out, out_idx, loss, hist);
    vq_final<<<dim3(1), dim3(512), 0, stream>>>(hist, loss, out);
}

// Round 28
// 220.771 us; speedup vs baseline: 1.3880x; 1.0165x over previous
//
#include <hip/hip_runtime.h>
#include <math.h>

#define NROWS 65536
#define DFULL 512
#define HHEADS 8
#define KCODES 512
#define HDIM 64
#define DELTA_S 5e-5f   // S-space cert threshold; cert bound ~1e-5, 5x margin

// ws layout (bytes)
#define WS_LOSS  0          // 64 x f64 slots, 64B stride -> 4096
#define WS_CNT   4096       // u32 padded counter -> 4160
#define WS_HIST  4160       // u32[4096] -> 20544
#define WS_T3    20544      // f32[4096] -> 36928
#define WS_BFRAG 36928      // ushort[8*32*2048] 1MB -> 1085504
#define WS_WL    1085504    // u32[524288] packed (row<<3|h) 2MB -> 3182656
#define WS_CBT   3182656    // f32[8][64][512] transposed codebook 1MB -> 4231232

typedef short bf16x8 __attribute__((ext_vector_type(8)));
typedef float f32x4 __attribute__((ext_vector_type(4)));

__device__ __forceinline__ unsigned short f2bf(float f) {
    unsigned u = __float_as_uint(f);
    unsigned r = (u + 0x7FFFu + ((u >> 16) & 1u)) >> 16;
    return (unsigned short)r;
}
__device__ __forceinline__ float bf2f(unsigned short b) {
    return __uint_as_float(((unsigned)b) << 16);
}

// hi/lo bf16 split of 8 floats via v_cvt_pk_bf16_f32 (HW RNE, == f2bf bitwise)
__device__ __forceinline__ void build_frag(const float* zp, bf16x8& hi, bf16x8& lo) {
    float4 a0 = *(const float4*)zp;
    float4 a1 = *(const float4*)(zp + 4);
    float v[8] = {a0.x, a0.y, a0.z, a0.w, a1.x, a1.y, a1.z, a1.w};
    union { unsigned u[4]; bf16x8 s; } H, L;
    #pragma unroll
    for (int j = 0; j < 4; ++j) {
        asm("v_cvt_pk_bf16_f32 %0, %1, %2"
            : "=v"(H.u[j]) : "v"(v[2 * j]), "v"(v[2 * j + 1]));
        float h0 = __uint_as_float(H.u[j] << 16);
        float h1 = __uint_as_float(H.u[j] & 0xffff0000u);
        float l0 = __fsub_rn(v[2 * j], h0);
        float l1 = __fsub_rn(v[2 * j + 1], h1);
        asm("v_cvt_pk_bf16_f32 %0, %1, %2"
            : "=v"(L.u[j]) : "v"(l0), "v"(l1));
    }
    hi = H.s; lo = L.s;
}

// ---------- fused prep: bfrag (blocks 0-255), cbT (256-1279), t3 (1280-1295) ----------
__global__ void vq_prep_all(const float* __restrict__ cb, float* __restrict__ t3,
                            float* __restrict__ cbT, unsigned short* __restrict__ bfrag) {
    const int b = blockIdx.x;
    const int tid = threadIdx.x;
    if (b < 256) {
        int t = b * 256 + tid;
        int lane = t & 63;
        int pass = (t >> 6) & 1;
        int khalf = (t >> 7) & 1;
        int kt = (t >> 8) & 31;
        int h = t >> 13;
        int n = lane & 15, kg = lane >> 4;
        int kcode = kt * 16 + n;
        int d0 = khalf * 32 + kg * 8;
        const float* src = cb + ((size_t)(h * KCODES + kcode)) * HDIM + d0;
        unsigned short o[8];
        #pragma unroll
        for (int j = 0; j < 8; ++j) {
            float v = src[j];
            unsigned short hi = f2bf(v);
            o[j] = (pass == 0) ? hi : f2bf(__fsub_rn(v, bf2f(hi)));
        }
        *(bf16x8*)(bfrag + (size_t)t * 8) = *(const bf16x8*)o;
    } else if (b < 1280) {
        int t = (b - 256) * 256 + tid;
        int h = t >> 15;
        int d = (t >> 9) & 63;
        int k = t & 511;
        cbT[t] = cb[((size_t)(h * KCODES + k)) * HDIM + d];
    } else {
        int row = (b - 1280) * 256 + tid;
        if (row < HHEADS * KCODES) {
            const float* c = cb + (size_t)row * HDIM;
            float s = __fmul_rn(c[0], c[0]);
            for (int i = 1; i < 64; ++i) s = __fadd_rn(s, __fmul_rn(c[i], c[i]));
            t3[row] = s;
        }
    }
}

// ---------- MFMA prefilter (LDS A-frags, dbuf b-frags) + fused gather ----------
__global__ __launch_bounds__(256, 4) void vq_prefilter(
    const float* __restrict__ z_e, const float* __restrict__ cb,
    const unsigned short* __restrict__ bfrag, const float* __restrict__ t3,
    float* __restrict__ out, float* __restrict__ out_idx,
    unsigned* __restrict__ cnt, unsigned* __restrict__ wl,
    double* __restrict__ loss, unsigned* __restrict__ hist) {
    // A-frag store: 4 waves x 8 frags x 64 lanes x 8 ushorts = 32 KB
    __shared__ __align__(16) unsigned short sA[4][8][64 * 8];
    const int l = threadIdx.x & 63;
    const int wv = threadIdx.x >> 6;
    const int h = blockIdx.x & 7;
    const int wg = (blockIdx.x >> 3) * 4 + wv;   // 0..2047, 32-row group
    const size_t rowbase = (size_t)wg * 32;
    const int m = l & 15, kg = l >> 4;

    // Build frags once and park them in LDS (wave-local region, no barrier).
    {
        bf16x8 hi, lo;
        #pragma unroll
        for (int t = 0; t < 2; ++t) {
            const float* zp = z_e + (rowbase + t * 16 + m) * DFULL + (size_t)h * HDIM + kg * 8;
            build_frag(zp, hi, lo);
            *(bf16x8*)&sA[wv][t * 4 + 0][l * 8] = hi;   // Ah0[t]
            *(bf16x8*)&sA[wv][t * 4 + 1][l * 8] = lo;   // Al0[t]
            build_frag(zp + 32, hi, lo);
            *(bf16x8*)&sA[wv][t * 4 + 2][l * 8] = hi;   // Ah1[t]
            *(bf16x8*)&sA[wv][t * 4 + 3][l * 8] = lo;   // Al1[t]
        }
    }

    const float* t3h = t3 + (size_t)h * KCODES;
    const unsigned short* bf_h = bfrag + (size_t)h * 32 * 2048;

    float m1[8], m2[8];
    int k1[8];
    #pragma unroll
    for (int s = 0; s < 8; ++s) { m1[s] = -INFINITY; m2[s] = -INFINITY; k1[s] = 0; }

    // software prefetch: kt=0 b-frags + t3 in flight before the loop
    bf16x8 c0 = *(const bf16x8*)(bf_h + l * 8);
    bf16x8 c1 = *(const bf16x8*)(bf_h + 512 + l * 8);
    bf16x8 c2 = *(const bf16x8*)(bf_h + 1024 + l * 8);
    bf16x8 c3 = *(const bf16x8*)(bf_h + 1536 + l * 8);
    float tv = t3h[m];

    #pragma unroll 2
    for (int kt = 0; kt < 32; ++kt) {
        // issue kt+1 loads before consuming kt (initialized tail: no UB)
        bf16x8 n0 = c0, n1 = c1, n2 = c2, n3 = c3;
        float tvn = tv;
        if (kt < 31) {
            const unsigned short* np_ = bf_h + (size_t)(kt + 1) * 2048;
            n0 = *(const bf16x8*)(np_ + l * 8);
            n1 = *(const bf16x8*)(np_ + 512 + l * 8);
            n2 = *(const bf16x8*)(np_ + 1024 + l * 8);
            n3 = *(const bf16x8*)(np_ + 1536 + l * 8);
            tvn = t3h[(kt + 1) * 16 + m];
        }
        float nht = __fmul_rn(-0.5f, tv);
        int kb = kt * 16 + m;
        #pragma unroll
        for (int t = 0; t < 2; ++t) {
            // A-frags from LDS: cheap ds_read reload each kt (lgkm pipe).
            bf16x8 Ah0 = *(const bf16x8*)&sA[wv][t * 4 + 0][l * 8];
            bf16x8 Al0 = *(const bf16x8*)&sA[wv][t * 4 + 1][l * 8];
            bf16x8 Ah1 = *(const bf16x8*)&sA[wv][t * 4 + 2][l * 8];
            bf16x8 Al1 = *(const bf16x8*)&sA[wv][t * 4 + 3][l * 8];
            f32x4 acc;
            acc[0] = nht; acc[1] = nht; acc[2] = nht; acc[3] = nht;
            acc = __builtin_amdgcn_mfma_f32_16x16x32_bf16(Ah0, c1, acc, 0, 0, 0);
            acc = __builtin_amdgcn_mfma_f32_16x16x32_bf16(Al0, c0, acc, 0, 0, 0);
            acc = __builtin_amdgcn_mfma_f32_16x16x32_bf16(Ah0, c0, acc, 0, 0, 0);
            acc = __builtin_amdgcn_mfma_f32_16x16x32_bf16(Ah1, c3, acc, 0, 0, 0);
            acc = __builtin_amdgcn_mfma_f32_16x16x32_bf16(Al1, c2, acc, 0, 0, 0);
            acc = __builtin_amdgcn_mfma_f32_16x16x32_bf16(Ah1, c2, acc, 0, 0, 0);
            #pragma unroll
            for (int j = 0; j < 4; ++j) {
                const int s = t * 4 + j;
                float S = acc[j];
                float m1o = m1[s];
                m2[s] = fmaxf(m2[s], fminf(S, m1o));   // branchless 2nd-max
                k1[s] = (S > m1o) ? kb : k1[s];
                m1[s] = fmaxf(m1o, S);
            }
        }
        c0 = n0; c1 = n1; c2 = n2; c3 = n3; tv = tvn;
    }

    #pragma unroll
    for (int off = 1; off <= 8; off <<= 1) {
        #pragma unroll
        for (int s = 0; s < 8; ++s) {
            float p1 = __shfl_xor(m1[s], off, 64);
            float p2 = __shfl_xor(m2[s], off, 64);
            int pk = __shfl_xor(k1[s], off, 64);
            float nm2 = fmaxf(fminf(m1[s], p1), fmaxf(m2[s], p2));
            bool g = p1 > m1[s];
            k1[s] = g ? pk : k1[s];
            m1[s] = g ? p1 : m1[s];
            m2[s] = nm2;
        }
    }
    // ties (m1==m2) are never certified -> exact recheck resolves first-index.

    unsigned mask = 0;      // bits s (writer-lane local)
    unsigned rowmask = 0;   // bits r = t*16 + kg*4 + j
    if (m == 0) {
        #pragma unroll
        for (int t = 0; t < 2; ++t) {
            #pragma unroll
            for (int j = 0; j < 4; ++j) {
                const int s = t * 4 + j;
                size_t row = rowbase + t * 16 + kg * 4 + j;   // C/D row=(l>>4)*4+j
                out_idx[row * HHEADS + h] = (float)k1[s];
                if (!((m1[s] - m2[s]) > DELTA_S)) {
                    mask |= (1u << s);
                    rowmask |= (1u << (t * 16 + kg * 4 + j));
                }
            }
        }
    }
    int nf = __popc(mask);
    int c0i = __shfl(nf, 0, 64), c1i = __shfl(nf, 16, 64);
    int c2i = __shfl(nf, 32, 64), c3i = __shfl(nf, 48, 64);
    int tot = c0i + c1i + c2i + c3i;
    unsigned base = 0;
    if (l == 0 && tot) base = atomicAdd(cnt, (unsigned)tot);
    base = (unsigned)__shfl((int)base, 0, 64);
    if (m == 0 && mask) {
        unsigned off = base + (kg > 0 ? c0i : 0) + (kg > 1 ? c1i : 0) + (kg > 2 ? c2i : 0);
        unsigned mk = mask;
        while (mk) {
            int s = __builtin_ctz(mk);
            mk &= mk - 1;
            unsigned row = (unsigned)rowbase + (unsigned)((s >> 2) * 16 + kg * 4 + (s & 3));
            wl[off++] = (row << 3) | (unsigned)h;
        }
    }
    rowmask |= __shfl_xor(rowmask, 16, 64);
    rowmask |= __shfl_xor(rowmask, 32, 64);
    rowmask = (unsigned)__shfl((int)rowmask, 0, 64);

    // fused gather, float4-vectorized with STATIC slot index; unconditional
    // z_q write (recheck overwrites flagged); loss/hist predicated on flag.
    const float* cbh = cb + (size_t)h * KCODES * HDIM;
    const int sub = l >> 4;        // row-in-quad group
    const int dq = l & 15;         // d-quad
    double lsum = 0.0;
    #pragma unroll
    for (int t = 0; t < 2; ++t) {
        #pragma unroll
        for (int j = 0; j < 4; ++j) {
            const int s = t * 4 + j;                     // static
            int r = t * 16 + sub * 4 + j;                // lane-dependent row
            int ir = __shfl(k1[s], sub * 16, 64);        // writer lane kg*16
            bool fl = (rowmask >> r) & 1u;
            float4 cv = *(const float4*)(cbh + (size_t)ir * HDIM + dq * 4);
            size_t ro = (rowbase + r) * DFULL + (size_t)h * HDIM + dq * 4;
            float4 ze = *(const float4*)(z_e + ro);
            float4 df, oo;
            df.x = __fsub_rn(cv.x, ze.x); oo.x = __fadd_rn(ze.x, df.x);
            df.y = __fsub_rn(cv.y, ze.y); oo.y = __fadd_rn(ze.y, df.y);
            df.z = __fsub_rn(cv.z, ze.z); oo.z = __fadd_rn(ze.z, df.z);
            df.w = __fsub_rn(cv.w, ze.w); oo.w = __fadd_rn(ze.w, df.w);
            *(float4*)(out + ro) = oo;
            if (!fl) {
                lsum += (double)df.x * (double)df.x + (double)df.y * (double)df.y
                      + (double)df.z * (double)df.z + (double)df.w * (double)df.w;
                if (dq == 0) atomicAdd(&hist[h * KCODES + ir], 1u);
            }
        }
    }
    #pragma unroll
    for (int off = 32; off; off >>= 1) lsum += __shfl_xor(lsum, off, 64);
    if (l == 0) atomicAdd(&loss[(wg & 63) * 8], lsum);   // padded slot
}

// ---------- exact recheck + finish for flagged rows ----------
__global__ __launch_bounds__(256, 2) void vq_recheck(
    const float* __restrict__ z_e, const float* __restrict__ cb,
    const float* __restrict__ cbT, const float* __restrict__ t3,
    const unsigned* __restrict__ cnt, const unsigned* __restrict__ wl,
    float* __restrict__ out, float* __restrict__ out_idx,
    double* __restrict__ loss, unsigned* __restrict__ hist) {
    const int lane = threadIdx.x & 63;
    const unsigned wid = blockIdx.x * (blockDim.x >> 6) + (threadIdx.x >> 6);
    const unsigned nw = gridDim.x * (blockDim.x >> 6);
    const unsigned n = cnt[0];
    double lsum = 0.0;                                   // per-wave loss accum
    for (unsigned i = wid; i < n; i += nw) {
        unsigned e = wl[i];
        int h = (int)(e & 7u);
        int row = (int)(e >> 3);
        const float* zp = z_e + (size_t)row * DFULL + (size_t)h * HDIM;   // wave-uniform
        float t1e = __fmul_rn(zp[0], zp[0]);
        #pragma unroll
        for (int d = 1; d < 64; ++d) t1e = __fadd_rn(t1e, __fmul_rn(zp[d], zp[d]));
        const float* ct = cbT + (size_t)h * (HDIM * KCODES);
        float a0 = 0.f, a1 = 0.f, a2 = 0.f, a3 = 0.f;
        float a4 = 0.f, a5 = 0.f, a6 = 0.f, a7 = 0.f;
        #pragma unroll 4
        for (int d = 0; d < 64; ++d) {
            float s = zp[d];                               // uniform
            const float* cd = ct + (size_t)d * KCODES + lane;
            a0 = __fmaf_rn(s, cd[0],   a0);
            a1 = __fmaf_rn(s, cd[64],  a1);
            a2 = __fmaf_rn(s, cd[128], a2);
            a3 = __fmaf_rn(s, cd[192], a3);
            a4 = __fmaf_rn(s, cd[256], a4);
            a5 = __fmaf_rn(s, cd[320], a5);
            a6 = __fmaf_rn(s, cd[384], a6);
            a7 = __fmaf_rn(s, cd[448], a7);
        }
        const float* t3h = t3 + (size_t)h * KCODES;
        float bd = INFINITY;
        int bk = 0x7FFFFFFF;
        float av[8] = {a0, a1, a2, a3, a4, a5, a6, a7};
        #pragma unroll
        for (int c = 0; c < 8; ++c) {
            int k = c * 64 + lane;
            float dk = __fadd_rn(__fsub_rn(t1e, __fmul_rn(2.0f, av[c])), t3h[k]);
            if (dk < bd) { bd = dk; bk = k; }   // ascending k within lane
        }
        #pragma unroll
        for (int off = 1; off <= 32; off <<= 1) {
            float pv = __shfl_xor(bd, off, 64);
            int   pk = __shfl_xor(bk, off, 64);
            if (pv < bd || (pv == bd && pk < bk)) { bd = pv; bk = pk; }
        }
        // finish this row (idx + z_q + loss accum + hist)
        if (lane == 0) out_idx[(size_t)row * HHEADS + h] = (float)bk;
        float cv = cb[((size_t)(h * KCODES + bk)) * HDIM + lane];
        float ze = zp[lane];
        float df = __fsub_rn(cv, ze);
        out[(size_t)row * DFULL + (size_t)h * HDIM + lane] = __fadd_rn(ze, df);
        lsum += (double)df * (double)df;
        if (lane == 0) atomicAdd(&hist[h * KCODES + bk], 1u);
    }
    #pragma unroll
    for (int off = 32; off; off >>= 1) lsum += __shfl_xor(lsum, off, 64);
    if (lane == 0 && lsum != 0.0) atomicAdd(&loss[(wid & 63) * 8], lsum);
}

__global__ void vq_final(const unsigned* __restrict__ hist,
                         const double* __restrict__ loss,
                         float* __restrict__ out) {
    const int tid = threadIdx.x;
    const int wave = tid >> 6;
    const int lane = tid & 63;
    __shared__ double perp[HHEADS];
    double e = 0.0;
    for (int k = lane; k < KCODES; k += 64) {
        double p = (double)hist[wave * KCODES + k] / (double)NROWS;
        e += p * log(p + 1e-10);
    }
    #pragma unroll
    for (int off = 32; off; off >>= 1) e += __shfl_xor(e, off, 64);
    if (lane == 0) perp[wave] = exp(-e);
    __syncthreads();
    if (tid == 0) {
        double mm = 0.0;
        #pragma unroll
        for (int i = 0; i < HHEADS; ++i) mm += perp[i];
        mm /= (double)HHEADS;
        double S = 0.0;
        for (int i = 0; i < 64; ++i) S += loss[i * 8];   // padded slots
        double cl = S / ((double)NROWS * (double)DFULL);
        size_t base = (size_t)NROWS * DFULL + (size_t)NROWS * HHEADS;
        out[base + 0] = (float)cl;
        out[base + 1] = (float)(0.1 * cl);
        out[base + 2] = (float)mm;
    }
}

extern "C" void kernel_launch(void* const* d_in, const int* in_sizes, int n_in,
                              void* d_out, int out_size, void* d_ws, size_t ws_size,
                              hipStream_t stream) {
    const float* z_e = (const float*)d_in[0];
    const float* cb  = (const float*)d_in[1];
    float* out = (float*)d_out;
    float* out_idx = out + (size_t)NROWS * DFULL;
    char* ws = (char*)d_ws;
    double* loss   = (double*)(ws + WS_LOSS);
    unsigned* cnt  = (unsigned*)(ws + WS_CNT);
    unsigned* hist = (unsigned*)(ws + WS_HIST);
    float* t3      = (float*)(ws + WS_T3);
    unsigned short* bfrag = (unsigned short*)(ws + WS_BFRAG);
    unsigned* wl   = (unsigned*)(ws + WS_WL);
    float* cbT     = (float*)(ws + WS_CBT);

    // zero loss slots + counter + histogram
    hipMemsetAsync(ws, 0, WS_HIST + (size_t)HHEADS * KCODES * 4, stream);

    vq_prep_all<<<dim3(1296), dim3(256), 0, stream>>>(cb, t3, cbT, bfrag);
    // 32 rows/wave: 16384 waves = 4096 blocks x 4 waves
    vq_prefilter<<<dim3(4096), dim3(256), 0, stream>>>(z_e, cb, bfrag, t3, out,
                                                       out_idx, cnt, wl, loss, hist);
    vq_recheck<<<dim3(2048), dim3(256), 0, stream>>>(z_e, cb, cbT, t3, cnt, wl,
                                                     out, out_idx, loss, hist);
    vq_final<<<dim3(1), dim3(512), 0, stream>>>(hist, loss, out);
}